// Round 8
// baseline (772.629 us; speedup 1.0000x reference)
//
#include <hip/hip_runtime.h>
#include <hip/hip_bf16.h>

#define EPS 1e-6f
#define L2E 1.4426950408889634f

typedef float f32x4 __attribute__((ext_vector_type(4)));
typedef short bf16x8 __attribute__((ext_vector_type(8)));

// ---------------------------------------------------------------------------
// DPP / cross-lane helpers
// ---------------------------------------------------------------------------
template <int CTRL>
__device__ __forceinline__ float dpp_mov(float v) {
  return __int_as_float(
      __builtin_amdgcn_update_dpp(0, __float_as_int(v), CTRL, 0xF, 0xF, true));
}

// 16-lane-row sum: 4 row_ror hops; every lane of each 16-group gets the
// group total. All-VALU.
__device__ __forceinline__ float reduce16(float v) {
  v += dpp_mov<0x121>(v);  // row_ror:1
  v += dpp_mov<0x122>(v);  // row_ror:2
  v += dpp_mov<0x124>(v);  // row_ror:4
  v += dpp_mov<0x128>(v);  // row_ror:8
  return v;
}

// Full 64-lane all-lanes sum.
// Fast path (gfx950): reduce16 + permlane16_swap + permlane32_swap.
//   swap(v,v) returns (r0,r1) with r0+r1 = v[l] + v[l^dist] at every lane.
// Fallback: round-5-proven bcast15/31 + readlane(63).
__device__ __forceinline__ float reduce64_all(float v) {
  v = reduce16(v);
#if __has_builtin(__builtin_amdgcn_permlane16_swap) && \
    __has_builtin(__builtin_amdgcn_permlane32_swap)
  {
    auto r = __builtin_amdgcn_permlane16_swap(__float_as_int(v),
                                              __float_as_int(v), false, false);
    v = __int_as_float(r[0]) + __int_as_float(r[1]);
  }
  {
    auto r = __builtin_amdgcn_permlane32_swap(__float_as_int(v),
                                              __float_as_int(v), false, false);
    v = __int_as_float(r[0]) + __int_as_float(r[1]);
  }
  return v;
#else
  v += dpp_mov<0x142>(v);  // row_bcast15
  v += dpp_mov<0x143>(v);  // row_bcast31 -> lanes 48..63 hold total
  return __int_as_float(__builtin_amdgcn_readlane(__float_as_int(v), 63));
#endif
}

__device__ __forceinline__ float sigm_b(float x, float nb) {
  float t = __builtin_amdgcn_exp2f(fmaf(x, -L2E, nb));
  return __builtin_amdgcn_rcpf(1.0f + t);
}
__device__ __forceinline__ float sigm(float x) {
  float t = __builtin_amdgcn_exp2f(x * -L2E);
  return __builtin_amdgcn_rcpf(1.0f + t);
}

// ---------------------------------------------------------------------------
// bf16 hi/lo split helpers. u32 element = (lo16 << 16) | hi16.
// ---------------------------------------------------------------------------
__device__ __forceinline__ unsigned f2bf(float x) {
  __hip_bfloat16 h = __float2bfloat16(x);
  return *reinterpret_cast<unsigned short*>(&h);
}
__device__ __forceinline__ unsigned split_pack(float x) {
  unsigned hi = f2bf(x);
  unsigned short hs = (unsigned short)hi;
  float hif = __bfloat162float(*reinterpret_cast<__hip_bfloat16*>(&hs));
  unsigned lo = f2bf(x - hif);
  return (lo << 16) | hi;
}

union FragCast { unsigned u[4]; bf16x8 v; };

// ---------------------------------------------------------------------------
// Kernel 1: proj = x @ W^T via bf16-split MFMA, with FUSED k/m row
// normalization in the epilogue (replaces the normalize_km kernel).
// Wave-col 0 holds cols 0-63 (k), wave-col 3 holds cols 192-255 (m):
// a row's 64 cols live in 16 lanes x 4 nf-regs -> sumsq via 4 fma + reduce16.
// ---------------------------------------------------------------------------
constexpr int GBM = 128, GBK = 32;

__global__ __launch_bounds__(512) void proj_gemm_mfma(
    const float* __restrict__ A,   // [M][1024]  x
    const float* __restrict__ Bw,  // [256][1024] W_kvqm
    float* __restrict__ C,         // [M][256]   proj
    int M, int K) {
  __shared__ unsigned As[GBM * GBK];
  __shared__ unsigned Bs[256 * GBK];

  const int tid  = threadIdx.x;
  const int lane = tid & 63;
  const int wid  = tid >> 6;
  const int m0   = blockIdx.x * GBM;
  const int wm   = (wid >> 2) * 64;
  const int wn   = (wid & 3) * 64;

  const int ar = tid >> 2, ak = (tid & 3) * 8;
  const int br = tid >> 1, bk = (tid & 1) * 16;

  f32x4 acc[4][4] = {};

  for (int k0 = 0; k0 < K; k0 += GBK) {
    {
      const float* src = &A[(size_t)(m0 + ar) * K + k0 + ak];
      float4 v0 = *(const float4*)(src);
      float4 v1 = *(const float4*)(src + 4);
      unsigned p0[4] = {split_pack(v0.x), split_pack(v0.y),
                        split_pack(v0.z), split_pack(v0.w)};
      unsigned p1[4] = {split_pack(v1.x), split_pack(v1.y),
                        split_pack(v1.z), split_pack(v1.w)};
      unsigned swz  = (unsigned)(ar & 7) << 4;
      char* base = (char*)As + ar * 128;
      *(uint4*)(base + (((unsigned)ak * 4) ^ swz))       = *(uint4*)p0;
      *(uint4*)(base + (((unsigned)(ak + 4) * 4) ^ swz)) = *(uint4*)p1;
    }
    {
      const float* src = &Bw[(size_t)br * K + k0 + bk];
      unsigned swz = (unsigned)(br & 7) << 4;
      char* base = (char*)Bs + br * 128;
#pragma unroll
      for (int q = 0; q < 4; ++q) {
        float4 v = *(const float4*)(src + q * 4);
        unsigned p[4] = {split_pack(v.x), split_pack(v.y),
                         split_pack(v.z), split_pack(v.w)};
        *(uint4*)(base + (((unsigned)(bk + q * 4) * 4) ^ swz)) = *(uint4*)p;
      }
    }
    __syncthreads();

    unsigned ah[4][4], al[4][4];
    const unsigned ko = ((unsigned)(lane >> 4)) * 16;
#pragma unroll
    for (int mf = 0; mf < 4; ++mf) {
      int r = wm + mf * 16 + (lane & 15);
      unsigned swz = (unsigned)(r & 7) << 4;
      char* base = (char*)As + r * 128;
      uint4 w0 = *(uint4*)(base + (ko ^ swz));
      uint4 w1 = *(uint4*)(base + ((64 + ko) ^ swz));
      ah[mf][0] = __builtin_amdgcn_perm(w0.y, w0.x, 0x05040100);
      al[mf][0] = __builtin_amdgcn_perm(w0.y, w0.x, 0x07060302);
      ah[mf][1] = __builtin_amdgcn_perm(w0.w, w0.z, 0x05040100);
      al[mf][1] = __builtin_amdgcn_perm(w0.w, w0.z, 0x07060302);
      ah[mf][2] = __builtin_amdgcn_perm(w1.y, w1.x, 0x05040100);
      al[mf][2] = __builtin_amdgcn_perm(w1.y, w1.x, 0x07060302);
      ah[mf][3] = __builtin_amdgcn_perm(w1.w, w1.z, 0x05040100);
      al[mf][3] = __builtin_amdgcn_perm(w1.w, w1.z, 0x07060302);
    }

#pragma unroll
    for (int nf = 0; nf < 4; ++nf) {
      int r = wn + nf * 16 + (lane & 15);
      unsigned swz = (unsigned)(r & 7) << 4;
      char* base = (char*)Bs + r * 128;
      uint4 w0 = *(uint4*)(base + (ko ^ swz));
      uint4 w1 = *(uint4*)(base + ((64 + ko) ^ swz));
      FragCast bh, bl;
      bh.u[0] = __builtin_amdgcn_perm(w0.y, w0.x, 0x05040100);
      bl.u[0] = __builtin_amdgcn_perm(w0.y, w0.x, 0x07060302);
      bh.u[1] = __builtin_amdgcn_perm(w0.w, w0.z, 0x05040100);
      bl.u[1] = __builtin_amdgcn_perm(w0.w, w0.z, 0x07060302);
      bh.u[2] = __builtin_amdgcn_perm(w1.y, w1.x, 0x05040100);
      bl.u[2] = __builtin_amdgcn_perm(w1.y, w1.x, 0x07060302);
      bh.u[3] = __builtin_amdgcn_perm(w1.w, w1.z, 0x05040100);
      bl.u[3] = __builtin_amdgcn_perm(w1.w, w1.z, 0x07060302);
#pragma unroll
      for (int mf = 0; mf < 4; ++mf) {
        FragCast fah, fal;
        fah.u[0] = ah[mf][0]; fah.u[1] = ah[mf][1];
        fah.u[2] = ah[mf][2]; fah.u[3] = ah[mf][3];
        fal.u[0] = al[mf][0]; fal.u[1] = al[mf][1];
        fal.u[2] = al[mf][2]; fal.u[3] = al[mf][3];
        acc[mf][nf] = __builtin_amdgcn_mfma_f32_16x16x32_bf16(
            fah.v, bh.v, acc[mf][nf], 0, 0, 0);
        acc[mf][nf] = __builtin_amdgcn_mfma_f32_16x16x32_bf16(
            fah.v, bl.v, acc[mf][nf], 0, 0, 0);
        acc[mf][nf] = __builtin_amdgcn_mfma_f32_16x16x32_bf16(
            fal.v, bh.v, acc[mf][nf], 0, 0, 0);
      }
    }
    __syncthreads();
  }

  // ---- fused epilogue: normalize k (wave-col 0) and m (wave-col 3) rows ----
  float rn[4][4];
  const int wcol = wid & 3;
  if (wcol == 0 || wcol == 3) {
#pragma unroll
    for (int mf = 0; mf < 4; ++mf)
#pragma unroll
      for (int r = 0; r < 4; ++r) {
        float ss = acc[mf][0][r] * acc[mf][0][r];
        ss = fmaf(acc[mf][1][r], acc[mf][1][r], ss);
        ss = fmaf(acc[mf][2][r], acc[mf][2][r], ss);
        ss = fmaf(acc[mf][3][r], acc[mf][3][r], ss);
        ss = reduce16(ss);   // row's 64-col sumsq (16 lanes x 4 nf)
        rn[mf][r] = __builtin_amdgcn_rcpf(sqrtf(ss) + EPS);
      }
  } else {
#pragma unroll
    for (int mf = 0; mf < 4; ++mf)
#pragma unroll
      for (int r = 0; r < 4; ++r) rn[mf][r] = 1.0f;
  }

#pragma unroll
  for (int mf = 0; mf < 4; ++mf) {
    int row = m0 + wm + mf * 16 + (lane >> 4) * 4;
#pragma unroll
    for (int nf = 0; nf < 4; ++nf) {
      int col = wn + nf * 16 + (lane & 15);
#pragma unroll
      for (int r = 0; r < 4; ++r)
        C[(size_t)(row + r) * 256 + col] = acc[mf][nf][r] * rn[mf][r];
    }
  }
}

// ---------------------------------------------------------------------------
// Kernel 2: scan, ONE ROW PER WAVE (1024 waves -> all 4 SIMDs/CU busy).
// lane j holds S[b,row,j], G[b,row,j]. Reduce = reduce64_all (12 VALU ops).
// Depth-2 prefetch; gateS hoisted; sq-reduce before G update.
// Stores RAW sq; out_act applies x^2*sigmoid(x).
// ---------------------------------------------------------------------------
#define PSTR 4096  // floats per timestep in proj (16 b * 256)

__global__ __launch_bounds__(256) void e81_scan(
    const float* __restrict__ proj,  // [T][16][256] : khat|v|q|mhat
    const float* __restrict__ S0,
    const float* __restrict__ G0,
    const float* __restrict__ bsg,
    const float* __restrict__ bgg,
    float* __restrict__ dout,
    int T) {
  const int lane = threadIdx.x & 63;
  const int wave = threadIdx.x >> 6;          // 0..3
  const int b    = blockIdx.x >> 4;           // 0..15
  const int row  = ((blockIdx.x & 15) << 2) + wave;  // 0..63

  const size_t sgi = ((size_t)(b * 64 + row)) * 64 + lane;
  float S = S0[sgi];
  float G = G0[sgi];
  const float nbs = -bsg[row] * L2E;
  const float nbg = -bgg[row] * L2E;

  float* outp = dout;
  float* Sout = dout + (size_t)T * 16 * 64;
  float* Gout = Sout + 16 * 64 * 64;

  const float* pA = proj + b * 256;   // even t
  const float* pB = pA + PSTR;        // odd t
  float kA = pA[lane], qA = pA[128 + lane], mA = pA[192 + lane], vA = pA[64 + row];
  float kB = pB[lane], qB = pB[128 + lane], mB = pB[192 + lane], vB = pB[64 + row];

#define STEP(k_, q_, m_, v_, tidx)                                   \
  {                                                                  \
    float gs = sigm_b(G, nbs);          /* off critical path */      \
    float sr = reduce64_all(S * k_);                                 \
    float gr = reduce64_all(G * m_);                                 \
    float sdelta = v_ - sr;                                          \
    S = fmaf(gs, S, sdelta * k_);                                    \
    float sq = reduce64_all(S * q_);                                 \
    float gg = sigm_b(S, nbg);                                       \
    G = fmaf(gg, G, (sdelta - gr) * m_);                             \
    if (lane == 0) outp[(((size_t)(tidx) << 4) + b) * 64 + row] = sq;\
  }

  for (int t = 0; t < T; t += 2) {
    const float* pA2 = (t + 2 < T) ? (pA + 2 * PSTR) : pA;
    const float* pB2 = (t + 3 < T) ? (pB + 2 * PSTR) : pB;
    float kA2 = pA2[lane], qA2 = pA2[128 + lane], mA2 = pA2[192 + lane],
          vA2 = pA2[64 + row];
    float kB2 = pB2[lane], qB2 = pB2[128 + lane], mB2 = pB2[192 + lane],
          vB2 = pB2[64 + row];

    STEP(kA, qA, mA, vA, t)
    STEP(kB, qB, mB, vB, t + 1)

    kA = kA2; qA = qA2; mA = mA2; vA = vA2; pA = pA2;
    kB = kB2; qB = qB2; mB = mB2; vB = vB2; pB = pB2;
  }
#undef STEP

  Sout[sgi] = S;
  Gout[sgi] = G;
}

// ---------------------------------------------------------------------------
// Kernel 3: out = x^2 * sigmoid(x) elementwise over the raw sq values.
// ---------------------------------------------------------------------------
__global__ __launch_bounds__(256) void out_act(float* __restrict__ o, int n4) {
  int i = blockIdx.x * 256 + threadIdx.x;
  if (i < n4) {
    float4 x = *(float4*)(o + 4 * i);
    float4 r;
    r.x = x.x * x.x * sigm(x.x);
    r.y = x.y * x.y * sigm(x.y);
    r.z = x.z * x.z * sigm(x.z);
    r.w = x.w * x.w * sigm(x.w);
    *(float4*)(o + 4 * i) = r;
  }
}

// ---------------------------------------------------------------------------
extern "C" void kernel_launch(void* const* d_in, const int* in_sizes, int n_in,
                              void* d_out, int out_size, void* d_ws, size_t ws_size,
                              hipStream_t stream) {
  const float* x  = (const float*)d_in[0];
  const float* S0 = (const float*)d_in[1];
  const float* G0 = (const float*)d_in[2];
  const float* W  = (const float*)d_in[3];
  const float* bs = (const float*)d_in[4];
  const float* bg = (const float*)d_in[5];
  float* out = (float*)d_out;
  float* proj = (float*)d_ws;               // [M][256] = 32 MB

  const int B = 16, D = 1024;
  const int T = in_sizes[0] / (B * D);      // 2048
  const int M = T * B;                      // 32768

  proj_gemm_mfma<<<dim3(M / GBM), 512, 0, stream>>>(x, W, proj, M, D);

  e81_scan<<<dim3(256), 256, 0, stream>>>(proj, S0, G0, bs, bg, out, T);

  const int n4 = T * B * 64 / 4;            // 524288 float4s
  out_act<<<dim3((n4 + 255) / 256), 256, 0, stream>>>(out, n4);
}

// Round 10
// 758.995 us; speedup vs baseline: 1.0180x; 1.0180x over previous
//
#include <hip/hip_runtime.h>
#include <hip/hip_bf16.h>

#define EPS 1e-6f
#define L2E 1.4426950408889634f

typedef float f32x4 __attribute__((ext_vector_type(4)));
typedef short bf16x8 __attribute__((ext_vector_type(8)));

// ---------------------------------------------------------------------------
// DPP / cross-lane helpers
// ---------------------------------------------------------------------------
template <int CTRL>
__device__ __forceinline__ float dpp_mov(float v) {
  return __int_as_float(
      __builtin_amdgcn_update_dpp(0, __float_as_int(v), CTRL, 0xF, 0xF, true));
}

__device__ __forceinline__ float reduce16(float v) {
  v += dpp_mov<0x121>(v);  // row_ror:1
  v += dpp_mov<0x122>(v);  // row_ror:2
  v += dpp_mov<0x124>(v);  // row_ror:4
  v += dpp_mov<0x128>(v);  // row_ror:8
  return v;
}

// Full 64-lane all-lanes sum (HW-verified by round-8 bench).
__device__ __forceinline__ float reduce64_all(float v) {
  v = reduce16(v);
#if __has_builtin(__builtin_amdgcn_permlane16_swap) && \
    __has_builtin(__builtin_amdgcn_permlane32_swap)
  {
    auto r = __builtin_amdgcn_permlane16_swap(__float_as_int(v),
                                              __float_as_int(v), false, false);
    v = __int_as_float(r[0]) + __int_as_float(r[1]);
  }
  {
    auto r = __builtin_amdgcn_permlane32_swap(__float_as_int(v),
                                              __float_as_int(v), false, false);
    v = __int_as_float(r[0]) + __int_as_float(r[1]);
  }
  return v;
#else
  v += dpp_mov<0x142>(v);
  v += dpp_mov<0x143>(v);
  return __int_as_float(__builtin_amdgcn_readlane(__float_as_int(v), 63));
#endif
}

__device__ __forceinline__ float sigm_b(float x, float nb) {
  float t = __builtin_amdgcn_exp2f(fmaf(x, -L2E, nb));
  return __builtin_amdgcn_rcpf(1.0f + t);
}
__device__ __forceinline__ float sigm(float x) {
  float t = __builtin_amdgcn_exp2f(x * -L2E);
  return __builtin_amdgcn_rcpf(1.0f + t);
}

// ---------------------------------------------------------------------------
// Fast hi/lo split: hi = trunc16(x) (AND), lo = x - hi (exact), both
// truncated to bf16 -> pack = (lo16<<16)|hi16. 3 VALU. Residual ~2^-17.
// ---------------------------------------------------------------------------
__device__ __forceinline__ unsigned split_pack_fast(float x) {
  float hi = __int_as_float(__float_as_int(x) & 0xFFFF0000u);
  float lo = x - hi;
  return __builtin_amdgcn_perm(__float_as_int(lo), __float_as_int(x),
                               0x07060302);  // {lo.hi16, x.hi16}
}

union FragCast { unsigned u[4]; bf16x8 v; };

// ---------------------------------------------------------------------------
// Kernel 0: pre-pack W into the swizzled LDS-image layout, per 64-k tile:
//   image[tile=k>>6][r][...] : byte = tile*65536 + r*256
//                              + ((k_t>>2)*16 ^ ((r&7)<<4)) + (k_t&3)*4
// GEMM B-staging then is a raw 16B copy (zero conversion VALU in the loop).
// Wpk lives in d_out (intra-launch scratch; overwritten by e81_scan later).
// ---------------------------------------------------------------------------
__global__ __launch_bounds__(256) void w_pack(const float* __restrict__ W,
                                              unsigned* __restrict__ Wpk) {
  int idx = blockIdx.x * 256 + threadIdx.x;   // 256K elems
  int r = idx >> 10;
  int k = idx & 1023;
  unsigned p = split_pack_fast(W[idx]);
  int tile = k >> 6, kt = k & 63;
  unsigned byte = (unsigned)tile * 65536u + (unsigned)r * 256u +
                  ((((unsigned)kt >> 2) * 16u) ^ (((unsigned)r & 7u) << 4)) +
                  ((unsigned)kt & 3u) * 4u;
  *(unsigned*)((char*)Wpk + byte) = p;
}

// ---------------------------------------------------------------------------
// Kernel 1: proj = x @ W^T via bf16-split MFMA. BK=64, LDS 96KB.
// Fused k/m row normalization in epilogue.
// ---------------------------------------------------------------------------
constexpr int GBM = 128, GBK = 64;

__global__ __launch_bounds__(512) void proj_gemm_mfma(
    const float* __restrict__ A,        // [M][1024]  x
    const unsigned* __restrict__ Wpk,   // packed+swizzled W images
    float* __restrict__ C,              // [M][256]   proj
    int M, int K) {
  __shared__ unsigned As[GBM * GBK];    // 32 KB (row = 256 B)
  __shared__ unsigned Bs[256 * GBK];    // 64 KB

  const int tid  = threadIdx.x;
  const int lane = tid & 63;
  const int wid  = tid >> 6;
  const int m0   = blockIdx.x * GBM;
  const int wm   = (wid >> 2) * 64;
  const int wn   = (wid & 3) * 64;

  const int ar = tid >> 2, ak = (tid & 3) * 16;   // A: 4 thr/row, 16 elems

  f32x4 acc[4][4] = {};

  for (int t8 = 0; t8 < K / GBK; ++t8) {
    const int k0 = t8 * GBK;
    // ---- stage A: 128x64 fp32 -> fast-split u32, swizzled b128 writes ----
    {
      const float* src = &A[(size_t)(m0 + ar) * K + k0 + ak];
      unsigned swz = (unsigned)(ar & 7) << 4;
      char* base = (char*)As + ar * 256;
#pragma unroll
      for (int q = 0; q < 4; ++q) {
        float4 v = *(const float4*)(src + q * 4);
        unsigned p[4] = {split_pack_fast(v.x), split_pack_fast(v.y),
                         split_pack_fast(v.z), split_pack_fast(v.w)};
        *(uint4*)(base + (((unsigned)(ak + q * 4) * 4) ^ swz)) = *(uint4*)p;
      }
    }
    // ---- stage B: raw 64KB copy of pre-swizzled image ----
    {
      const char* gsrc = (const char*)Wpk + (size_t)t8 * 65536 + tid * 16;
      char* ldst = (char*)Bs + tid * 16;
#pragma unroll
      for (int i = 0; i < 8; ++i)
        *(uint4*)(ldst + i * 8192) = *(const uint4*)(gsrc + i * 8192);
    }
    __syncthreads();

#pragma unroll
    for (int g = 0; g < 2; ++g) {   // two K=32 sub-phases
      unsigned ah[4][4], al[4][4];
      const unsigned ko = g * 128 + ((unsigned)(lane >> 4)) * 16;
#pragma unroll
      for (int mf = 0; mf < 4; ++mf) {
        int r = wm + mf * 16 + (lane & 15);
        unsigned swz = (unsigned)(r & 7) << 4;
        char* base = (char*)As + r * 256;
        uint4 w0 = *(uint4*)(base + (ko ^ swz));
        uint4 w1 = *(uint4*)(base + ((64 + ko) ^ swz));
        ah[mf][0] = __builtin_amdgcn_perm(w0.y, w0.x, 0x05040100);
        al[mf][0] = __builtin_amdgcn_perm(w0.y, w0.x, 0x07060302);
        ah[mf][1] = __builtin_amdgcn_perm(w0.w, w0.z, 0x05040100);
        al[mf][1] = __builtin_amdgcn_perm(w0.w, w0.z, 0x07060302);
        ah[mf][2] = __builtin_amdgcn_perm(w1.y, w1.x, 0x05040100);
        al[mf][2] = __builtin_amdgcn_perm(w1.y, w1.x, 0x07060302);
        ah[mf][3] = __builtin_amdgcn_perm(w1.w, w1.z, 0x05040100);
        al[mf][3] = __builtin_amdgcn_perm(w1.w, w1.z, 0x07060302);
      }
#pragma unroll
      for (int nf = 0; nf < 4; ++nf) {
        int r = wn + nf * 16 + (lane & 15);
        unsigned swz = (unsigned)(r & 7) << 4;
        char* base = (char*)Bs + r * 256;
        uint4 w0 = *(uint4*)(base + (ko ^ swz));
        uint4 w1 = *(uint4*)(base + ((64 + ko) ^ swz));
        FragCast bh, bl;
        bh.u[0] = __builtin_amdgcn_perm(w0.y, w0.x, 0x05040100);
        bl.u[0] = __builtin_amdgcn_perm(w0.y, w0.x, 0x07060302);
        bh.u[1] = __builtin_amdgcn_perm(w0.w, w0.z, 0x05040100);
        bl.u[1] = __builtin_amdgcn_perm(w0.w, w0.z, 0x07060302);
        bh.u[2] = __builtin_amdgcn_perm(w1.y, w1.x, 0x05040100);
        bl.u[2] = __builtin_amdgcn_perm(w1.y, w1.x, 0x07060302);
        bh.u[3] = __builtin_amdgcn_perm(w1.w, w1.z, 0x05040100);
        bl.u[3] = __builtin_amdgcn_perm(w1.w, w1.z, 0x07060302);
#pragma unroll
        for (int mf = 0; mf < 4; ++mf) {
          FragCast fah, fal;
          fah.u[0] = ah[mf][0]; fah.u[1] = ah[mf][1];
          fah.u[2] = ah[mf][2]; fah.u[3] = ah[mf][3];
          fal.u[0] = al[mf][0]; fal.u[1] = al[mf][1];
          fal.u[2] = al[mf][2]; fal.u[3] = al[mf][3];
          acc[mf][nf] = __builtin_amdgcn_mfma_f32_16x16x32_bf16(
              fah.v, bh.v, acc[mf][nf], 0, 0, 0);
          acc[mf][nf] = __builtin_amdgcn_mfma_f32_16x16x32_bf16(
              fah.v, bl.v, acc[mf][nf], 0, 0, 0);
          acc[mf][nf] = __builtin_amdgcn_mfma_f32_16x16x32_bf16(
              fal.v, bh.v, acc[mf][nf], 0, 0, 0);
        }
      }
    }
    __syncthreads();
  }

  // ---- fused epilogue: normalize k (wave-col 0) and m (wave-col 3) rows ---
  float rn[4][4];
  const int wcol = wid & 3;
  if (wcol == 0 || wcol == 3) {
#pragma unroll
    for (int mf = 0; mf < 4; ++mf)
#pragma unroll
      for (int r = 0; r < 4; ++r) {
        float ss = acc[mf][0][r] * acc[mf][0][r];
        ss = fmaf(acc[mf][1][r], acc[mf][1][r], ss);
        ss = fmaf(acc[mf][2][r], acc[mf][2][r], ss);
        ss = fmaf(acc[mf][3][r], acc[mf][3][r], ss);
        ss = reduce16(ss);
        rn[mf][r] = __builtin_amdgcn_rcpf(sqrtf(ss) + EPS);
      }
  } else {
#pragma unroll
    for (int mf = 0; mf < 4; ++mf)
#pragma unroll
      for (int r = 0; r < 4; ++r) rn[mf][r] = 1.0f;
  }

#pragma unroll
  for (int mf = 0; mf < 4; ++mf) {
    int row = m0 + wm + mf * 16 + (lane >> 4) * 4;
#pragma unroll
    for (int nf = 0; nf < 4; ++nf) {
      int col = wn + nf * 16 + (lane & 15);
#pragma unroll
      for (int r = 0; r < 4; ++r)
        C[(size_t)(row + r) * 256 + col] = acc[mf][nf][r] * rn[mf][r];
    }
  }
}

// ---------------------------------------------------------------------------
// Kernel 2: scan. 1 row/wave, 8 waves/block (2/SIMD), 128 blocks.
// 3-batch rotating prefetch: loads issued ~4 steps ahead of use, fully
// static register naming (no copies of in-flight regs -> compiler can't
// collapse the pipeline). XCD-swizzled blockIdx: same-b blocks share L2.
// ---------------------------------------------------------------------------
#define PSTR 4096

__global__ __launch_bounds__(512) void e81_scan(
    const float* __restrict__ proj,
    const float* __restrict__ S0,
    const float* __restrict__ G0,
    const float* __restrict__ bsg,
    const float* __restrict__ bgg,
    float* __restrict__ dout,
    int T) {
  // swizzle: XCD (raw&7) gets 16 consecutive logical blocks -> 2 b-streams
  const int L = (blockIdx.x & 7) * 16 + (blockIdx.x >> 3);
  const int w = L * 8 + (threadIdx.x >> 6);   // 0..1023
  const int lane = threadIdx.x & 63;
  const int b   = w >> 6;
  const int row = w & 63;
  const int Tm1 = T - 1;
  const int bo  = b * 256;

  const size_t sgi = ((size_t)(b * 64 + row)) * 64 + lane;
  float S = S0[sgi];
  float G = G0[sgi];
  const float nbs = -bsg[row] * L2E;
  const float nbg = -bgg[row] * L2E;

  float* outp = dout;
  float* Sout = dout + (size_t)T * 16 * 64;
  float* Gout = Sout + 16 * 64 * 64;

#define DECLB(n) float kA##n, qA##n, mA##n, vA##n, kB##n, qB##n, mB##n, vB##n;
#define LOADB(n, tt)                                                        \
  {                                                                         \
    int _ta = (tt) < Tm1 ? (tt) : Tm1;                                      \
    int _tb = (tt) + 1 < Tm1 ? (tt) + 1 : Tm1;                              \
    const float* _pa = proj + (size_t)_ta * PSTR + bo;                      \
    const float* _pb = proj + (size_t)_tb * PSTR + bo;                      \
    kA##n = _pa[lane]; qA##n = _pa[128 + lane];                             \
    mA##n = _pa[192 + lane]; vA##n = _pa[64 + row];                         \
    kB##n = _pb[lane]; qB##n = _pb[128 + lane];                             \
    mB##n = _pb[192 + lane]; vB##n = _pb[64 + row];                         \
  }

#define STEP(k_, q_, m_, v_, tidx)                                          \
  {                                                                         \
    float gs = sigm_b(G, nbs);                                              \
    float sr = reduce64_all(S * k_);                                        \
    float gr = reduce64_all(G * m_);                                        \
    float sdelta = v_ - sr;                                                 \
    S = fmaf(gs, S, sdelta * k_);                                           \
    float sq = reduce64_all(S * q_);                                        \
    float gg = sigm_b(S, nbg);                                              \
    G = fmaf(gg, G, (sdelta - gr) * m_);                                    \
    if (lane == 0) outp[(((size_t)(tidx) << 4) + b) * 64 + row] = sq;       \
  }

#define BODY(nc, ni, tt)                                                    \
  LOADB(ni, (tt) + 4)                                                       \
  __builtin_amdgcn_sched_barrier(0);                                        \
  STEP(kA##nc, qA##nc, mA##nc, vA##nc, (tt))                                \
  STEP(kB##nc, qB##nc, mB##nc, vB##nc, (tt) + 1)

  DECLB(0) DECLB(1) DECLB(2)
  LOADB(0, 0)
  LOADB(1, 2)

  int t = 0;
  for (; t + 8 <= T; t += 6) {
    BODY(0, 2, t)
    BODY(1, 0, t + 2)
    BODY(2, 1, t + 4)
  }
  // T = 2048 = 6*341 + 2: tail = 2 steps, already loaded into batch 0.
  STEP(kA0, qA0, mA0, vA0, t)
  STEP(kB0, qB0, mB0, vB0, t + 1)

#undef BODY
#undef STEP
#undef LOADB
#undef DECLB

  Sout[sgi] = S;
  Gout[sgi] = G;
}

// ---------------------------------------------------------------------------
// Kernel 3: out = x^2 * sigmoid(x) elementwise over raw sq values.
// ---------------------------------------------------------------------------
__global__ __launch_bounds__(256) void out_act(float* __restrict__ o, int n4) {
  int i = blockIdx.x * 256 + threadIdx.x;
  if (i < n4) {
    float4 x = *(float4*)(o + 4 * i);
    float4 r;
    r.x = x.x * x.x * sigm(x.x);
    r.y = x.y * x.y * sigm(x.y);
    r.z = x.z * x.z * sigm(x.z);
    r.w = x.w * x.w * sigm(x.w);
    *(float4*)(o + 4 * i) = r;
  }
}

// ---------------------------------------------------------------------------
extern "C" void kernel_launch(void* const* d_in, const int* in_sizes, int n_in,
                              void* d_out, int out_size, void* d_ws, size_t ws_size,
                              hipStream_t stream) {
  const float* x  = (const float*)d_in[0];
  const float* S0 = (const float*)d_in[1];
  const float* G0 = (const float*)d_in[2];
  const float* W  = (const float*)d_in[3];
  const float* bs = (const float*)d_in[4];
  const float* bg = (const float*)d_in[5];
  float* out = (float*)d_out;
  float* proj = (float*)d_ws;               // 32 MiB (ws usage unchanged)
  // Wpk (1 MiB) lives in d_out: written by w_pack, read by the GEMM, then
  // overwritten by e81_scan's outputs. Stream-ordered, validated after.
  unsigned* Wpk = (unsigned*)d_out;

  const int B = 16, D = 1024;
  const int T = in_sizes[0] / (B * D);      // 2048
  const int M = T * B;                      // 32768

  w_pack<<<dim3(256 * 1024 / 256), 256, 0, stream>>>(W, Wpk);

  proj_gemm_mfma<<<dim3(M / GBM), 512, 0, stream>>>(x, Wpk, proj, M, D);

  e81_scan<<<dim3(128), 512, 0, stream>>>(proj, S0, G0, bs, bg, out, T);

  const int n4 = T * B * 64 / 4;
  out_act<<<dim3((n4 + 255) / 256), 256, 0, stream>>>(out, n4);
}